// Round 1
// baseline (342.442 us; speedup 1.0000x reference)
//
#include <hip/hip_runtime.h>

// upfirdn2d(x, k, up=2, down=1, pad=(2,1)) with k = outer([1,3,3,1])/16.
// Reduces to separable 2-tap-per-axis upsample:
//   even out coord 2r:   0.25*in[r-1] + 0.75*in[r]
//   odd  out coord 2r+1: 0.75*in[r]   + 0.25*in[r+1]
// (zero outside [0,64)).
// x: (16,256,64,64) f32  ->  out: (16,256,128,128) f32.

#define H_IN  64
#define W_IN  64
#define H_OUT 128
#define W_OUT 128

__global__ __launch_bounds__(256) void upsample_2x_kernel(
    const float* __restrict__ x, float* __restrict__ out, int total) {
  int idx = blockIdx.x * 256 + threadIdx.x;
  if (idx >= total) return;

  int q   = idx & 31;         // column quad: output cols 4q..4q+3
  int r   = (idx >> 5) & 63;  // input row: output rows 2r, 2r+1
  int img = idx >> 11;        // B*C image index (64*32 = 2048 = 2^11 threads/img)

  const float* xi = x + (size_t)img * (H_IN * W_IN);
  float*       oi = out + (size_t)img * (H_OUT * W_OUT);

  const int c = 2 * q;  // need input cols c-1, c, c+1, c+2 (c+1 <= 63 always)

  // Load 3 input rows (r-1, r, r+1) x 4 cols, zero at boundaries.
  float v[3][4];
#pragma unroll
  for (int i = 0; i < 3; ++i) {
    int row = r - 1 + i;
    bool rok = (row >= 0) & (row < H_IN);
    const float* xr = xi + row * W_IN;
    // aligned 8B load for the two center cols
    float2 m = rok ? *(const float2*)(xr + c) : make_float2(0.f, 0.f);
    v[i][1] = m.x;
    v[i][2] = m.y;
    v[i][0] = (rok && q != 0)  ? xr[c - 1] : 0.f;
    v[i][3] = (rok && q != 31) ? xr[c + 2] : 0.f;
  }

  // Horizontal pass: 4 output cols from 4 input cols.
  float h[3][4];
#pragma unroll
  for (int i = 0; i < 3; ++i) {
    h[i][0] = 0.25f * v[i][0] + 0.75f * v[i][1];  // x = 4q   (even)
    h[i][1] = 0.75f * v[i][1] + 0.25f * v[i][2];  // x = 4q+1 (odd)
    h[i][2] = 0.25f * v[i][1] + 0.75f * v[i][2];  // x = 4q+2 (even)
    h[i][3] = 0.75f * v[i][2] + 0.25f * v[i][3];  // x = 4q+3 (odd)
  }

  // Vertical pass: row 2r (even) and row 2r+1 (odd).
  float4 o0, o1;
  o0.x = 0.25f * h[0][0] + 0.75f * h[1][0];
  o0.y = 0.25f * h[0][1] + 0.75f * h[1][1];
  o0.z = 0.25f * h[0][2] + 0.75f * h[1][2];
  o0.w = 0.25f * h[0][3] + 0.75f * h[1][3];
  o1.x = 0.75f * h[1][0] + 0.25f * h[2][0];
  o1.y = 0.75f * h[1][1] + 0.25f * h[2][1];
  o1.z = 0.75f * h[1][2] + 0.25f * h[2][2];
  o1.w = 0.75f * h[1][3] + 0.25f * h[2][3];

  float* orow0 = oi + (2 * r) * W_OUT + 4 * q;
  float* orow1 = orow0 + W_OUT;
  *(float4*)orow0 = o0;
  *(float4*)orow1 = o1;
}

extern "C" void kernel_launch(void* const* d_in, const int* in_sizes, int n_in,
                              void* d_out, int out_size, void* d_ws, size_t ws_size,
                              hipStream_t stream) {
  const float* x = (const float*)d_in[0];
  float* out = (float*)d_out;
  // 16*256 images * 64 input rows * 32 col-quads = 8,388,608 threads
  const int total = 16 * 256 * 64 * 32;
  const int blocks = total / 256;  // 32768
  upsample_2x_kernel<<<blocks, 256, 0, stream>>>(x, out, total);
}

// Round 2
// 310.549 us; speedup vs baseline: 1.1027x; 1.1027x over previous
//
#include <hip/hip_runtime.h>

// upfirdn2d(x, k, up=2, down=1, pad=(2,1)), k = outer([1,3,3,1])/16.
// Separable per-axis (weights [1,3,3,1]/4 on zero-stuffed input):
//   out[2r]   = 0.25*in[r-1] + 0.75*in[r]
//   out[2r+1] = 0.75*in[r]   + 0.25*in[r+1]
// x: (16,256,64,64) f32 -> out: (16,256,128,128) f32.
//
// Each thread: 4x4 output tile (output rows 4t..4t+3, cols 4q..4q+3).
// Loads 4 input rows (2t-1..2t+2) as one aligned float2 each (cols 2q,2q+1);
// horizontal halos come from neighbor lanes via shfl. The lanes where the
// shfl crosses the 32-lane half-wave seam (q==0 left, q==31 right) are
// exactly the lanes that need boundary zeros, so the wrong-row pull is
// masked anyway.

__global__ __launch_bounds__(256) void upsample_2x_kernel(
    const float* __restrict__ x, float* __restrict__ out) {
  int idx = blockIdx.x * 256 + threadIdx.x;
  int q   = idx & 31;         // column quad: output cols 4q..4q+3, input cols 2q,2q+1
  int t   = (idx >> 5) & 31;  // row pair: input rows 2t,2t+1 -> output rows 4t..4t+3
  int img = idx >> 10;        // B*C image (32*32 = 1024 threads/img)

  const float* xi = x + (size_t)img * (64 * 64);
  float*       oi = out + (size_t)img * (128 * 128);

  const int c  = 2 * q;
  const int r0 = 2 * t;

  // 4 input rows: r0-1, r0, r0+1, r0+2 (zero outside [0,64))
  float2 m[4];
  m[0] = (t > 0)  ? *(const float2*)(xi + (r0 - 1) * 64 + c) : make_float2(0.f, 0.f);
  m[1] =            *(const float2*)(xi + (r0    ) * 64 + c);
  m[2] =            *(const float2*)(xi + (r0 + 1) * 64 + c);
  m[3] = (t < 31) ? *(const float2*)(xi + (r0 + 2) * 64 + c) : make_float2(0.f, 0.f);

  // Horizontal pass: input cols (c-1, c, c+1, c+2) -> output cols 4q..4q+3.
  float h[4][4];
#pragma unroll
  for (int i = 0; i < 4; ++i) {
    float left  = __shfl_up(m[i].y, 1);   // lane q-1's col c-1
    float right = __shfl_down(m[i].x, 1); // lane q+1's col c+2
    if (q == 0)  left  = 0.f;
    if (q == 31) right = 0.f;
    h[i][0] = 0.25f * left   + 0.75f * m[i].x;  // col 4q   (even)
    h[i][1] = 0.75f * m[i].x + 0.25f * m[i].y;  // col 4q+1 (odd)
    h[i][2] = 0.25f * m[i].x + 0.75f * m[i].y;  // col 4q+2 (even)
    h[i][3] = 0.75f * m[i].y + 0.25f * right;   // col 4q+3 (odd)
  }

  // Vertical pass -> 4 output rows.
  float* op = oi + (4 * t) * 128 + 4 * q;
  float4 o;

  o.x = 0.25f * h[0][0] + 0.75f * h[1][0];
  o.y = 0.25f * h[0][1] + 0.75f * h[1][1];
  o.z = 0.25f * h[0][2] + 0.75f * h[1][2];
  o.w = 0.25f * h[0][3] + 0.75f * h[1][3];
  *(float4*)(op) = o;                       // row 4t   (even, r=r0)

  o.x = 0.75f * h[1][0] + 0.25f * h[2][0];
  o.y = 0.75f * h[1][1] + 0.25f * h[2][1];
  o.z = 0.75f * h[1][2] + 0.25f * h[2][2];
  o.w = 0.75f * h[1][3] + 0.25f * h[2][3];
  *(float4*)(op + 128) = o;                 // row 4t+1 (odd,  r=r0)

  o.x = 0.25f * h[1][0] + 0.75f * h[2][0];
  o.y = 0.25f * h[1][1] + 0.75f * h[2][1];
  o.z = 0.25f * h[1][2] + 0.75f * h[2][2];
  o.w = 0.25f * h[1][3] + 0.75f * h[2][3];
  *(float4*)(op + 256) = o;                 // row 4t+2 (even, r=r0+1)

  o.x = 0.75f * h[2][0] + 0.25f * h[3][0];
  o.y = 0.75f * h[2][1] + 0.25f * h[3][1];
  o.z = 0.75f * h[2][2] + 0.25f * h[3][2];
  o.w = 0.75f * h[2][3] + 0.25f * h[3][3];
  *(float4*)(op + 384) = o;                 // row 4t+3 (odd,  r=r0+1)
}

extern "C" void kernel_launch(void* const* d_in, const int* in_sizes, int n_in,
                              void* d_out, int out_size, void* d_ws, size_t ws_size,
                              hipStream_t stream) {
  const float* x = (const float*)d_in[0];
  float* out = (float*)d_out;
  // 16*256 images * 32 row-pairs * 32 col-quads = 4,194,304 threads
  const int blocks = (16 * 256 * 32 * 32) / 256;  // 16384
  upsample_2x_kernel<<<blocks, 256, 0, stream>>>(x, out);
}